// Round 10
// baseline (481.691 us; speedup 1.0000x reference)
//
#include <hip/hip_runtime.h>
#include <math.h>

#define BATCH 2048
#define LATENT 64
#define LOG_2PI 1.8378770664093453f
#define BETA_M1 5.0f
#define LN2 0.69314718055994530942f
// C2 = -0.5 * log2(e)
#define C2 (-0.72134752044448170368f)

// ws layout (float units), ~3.2 MB:
//   Vt   [128][2048]  Vt[2l][j]=C2*inv, Vt[2l+1][j]=C2*m*inv
//   Tce  [64][2048]   Tce[l][j]=C2*(m^2*inv+lv+LOG2PI)
//   Up   [128][2048]  Up[2l][i]=z^2, Up[2l+1][i]=-2z
//   CE   [2048], KLP [2048]
//   RMP/RSP [4][2048] row-LSE partials per j-quarter (log2 domain)
//   PART [16]         [0]=unused, [2]=done counter
//   PPS  [64][2048]   per-(l,i) exp-sum accumulators (zeroed, atomicAdd)
#define OFF_VT   0
#define OFF_TCE  (128*BATCH)
#define OFF_UP   (OFF_TCE + 64*BATCH)
#define OFF_CE   (OFF_UP + 128*BATCH)
#define OFF_KLP  (OFF_CE + BATCH)
#define OFF_RMP  (OFF_KLP + BATCH)
#define OFF_RSP  (OFF_RMP + 4*BATCH)
#define OFF_PART (OFF_RSP + 4*BATCH)
#define OFF_PPS  (OFF_PART + 16)

// Precompute (R5-proven): 128 blocks x 256, LDS transpose, coalesced reads
// AND coalesced row-major writes. Zeroes PPS + PART.
__global__ __launch_bounds__(256) void pre_kernel(const float* __restrict__ z,
                                                  const float* __restrict__ zm,
                                                  const float* __restrict__ zlv,
                                                  float* __restrict__ ws) {
    __shared__ float Tz[16][65], Tm[16][65], Tlv[16][65];
    __shared__ float CEp[16][16], KLp[16][16];
    int t = threadIdx.x, lane = t & 63, w = t >> 6;
    int j0 = blockIdx.x * 16;

    *(float4*)(ws + OFF_PPS + (blockIdx.x * 256 + t) * 4) = make_float4(0.f, 0.f, 0.f, 0.f);
    if (blockIdx.x == 0 && t < 16) ws[OFF_PART + t] = 0.0f;

    #pragma unroll
    for (int p = 0; p < 4; ++p) {
        int jr = p * 4 + w;
        int idx = (j0 + jr) * LATENT + lane;
        Tz[jr][lane]  = z[idx];
        Tm[jr][lane]  = zm[idx];
        Tlv[jr][lane] = zlv[idx];
    }
    __syncthreads();

    int jl = t & 15, lg = t >> 4;
    int j = j0 + jl;
    float ce_acc = 0.0f, kl_acc = 0.0f;
    #pragma unroll
    for (int q = 0; q < 4; ++q) {
        int l = q * 16 + lg;
        float zv = Tz[jl][l];
        float m  = Tm[jl][l];
        float lv = Tlv[jl][l];
        float iv  = __expf(-lv);
        float civ = C2 * iv;
        float miv = m * iv;
        float cmv = C2 * miv;
        float cev = C2 * fmaf(m, miv, lv + LOG_2PI);
        ws[OFF_VT  + (2*l)   * BATCH + j] = civ;
        ws[OFF_VT  + (2*l+1) * BATCH + j] = cmv;
        ws[OFF_TCE + l       * BATCH + j] = cev;
        ws[OFF_UP  + (2*l)   * BATCH + j] = zv * zv;
        ws[OFF_UP  + (2*l+1) * BATCH + j] = -2.0f * zv;
        ce_acc += cev;
        kl_acc += fmaf(m, m, __expf(lv)) - lv - 1.0f;
    }
    CEp[lg][jl] = ce_acc;
    KLp[lg][jl] = kl_acc;
    __syncthreads();
    if (t < 16) {
        float ce = 0.0f, kl = 0.0f;
        #pragma unroll
        for (int g = 0; g < 16; ++g) { ce += CEp[g][t]; kl += KLp[g][t]; }
        ws[OFF_CE  + j0 + t] = ce;
        ws[OFF_KLP + j0 + t] = kl;
    }
}

// Main: 2048 uniform blocks, all co-resident (8 blocks/CU).
//   bx < 1024: dim path — l = bx>>4, jc = bx&15 (128-j chunk), 8 i/thread.
//   bx >= 1024: row path — 8 i, 512-j quarter, 2 j/thread.
// Last block to finish runs the full finalize and writes out[0].
__global__ __launch_bounds__(256, 8) void main_kernel(float* __restrict__ ws,
                                                      float* __restrict__ out) {
    __shared__ float RMs[8][4], RSs[8][4];
    __shared__ float s_tc[256], s_kl[256];
    __shared__ int is_last;
    int bx = blockIdx.x, t = threadIdx.x;

    if (bx < 1024) {
        // ---- dim path ----
        int l  = bx >> 4;
        int jc = bx & 15;

        const float* __restrict__ up0 = ws + OFF_UP + (2*l)   * BATCH;
        const float* __restrict__ up1 = ws + OFF_UP + (2*l+1) * BATCH;
        float z2[8], n2[8], s[8];
        #pragma unroll
        for (int k = 0; k < 8; ++k) {
            z2[k] = up0[t + 256*k];
            n2[k] = up1[t + 256*k];
            s[k]  = 0.0f;
        }

        const float* __restrict__ pc = ws + OFF_VT  + (2*l)   * BATCH + jc * 128;
        const float* __restrict__ pm = ws + OFF_VT  + (2*l+1) * BATCH + jc * 128;
        const float* __restrict__ pe = ws + OFF_TCE + l       * BATCH + jc * 128;

        for (int jj = 0; jj < 128; jj += 8) {
            #pragma unroll
            for (int u = 0; u < 8; ++u) {
                float cc = pc[jj + u];
                float mm = pm[jj + u];
                float ee = pe[jj + u];
                #pragma unroll
                for (int k = 0; k < 8; ++k)
                    s[k] += __builtin_amdgcn_exp2f(fmaf(z2[k], cc, fmaf(n2[k], mm, ee)));
            }
        }

        float* PPS = ws + OFF_PPS + l * BATCH;
        #pragma unroll
        for (int k = 0; k < 8; ++k)
            atomicAdd(&PPS[t + 256*k], s[k]);
    } else {
        // ---- row path ----
        int bx2 = bx - 1024;
        int ib8 = bx2 >> 2, qh = bx2 & 3;
        int i0 = ib8 * 8;
        int jb = qh * 512 + 2 * t;
        int lane = t & 63, w = t >> 6;

        const float* __restrict__ Vt = ws + OFF_VT;
        const float* __restrict__ Up = ws + OFF_UP;

        float r[8][2];
        #pragma unroll
        for (int i = 0; i < 8; ++i) r[i][0] = r[i][1] = 0.0f;

        for (int l = 0; l < LATENT; ++l) {
            float2 v0 = *(const float2*)(Vt + (2*l)   * BATCH + jb);
            float2 v1 = *(const float2*)(Vt + (2*l+1) * BATCH + jb);
            const float* __restrict__ u0 = Up + (2*l)   * BATCH + i0;  // uniform -> s_load
            const float* __restrict__ u1 = Up + (2*l+1) * BATCH + i0;  // uniform -> s_load
            #pragma unroll
            for (int i = 0; i < 8; ++i) {
                float a = u0[i], bb = u1[i];
                r[i][0] = fmaf(a, v0.x, fmaf(bb, v1.x, r[i][0]));
                r[i][1] = fmaf(a, v0.y, fmaf(bb, v1.y, r[i][1]));
            }
        }

        float2 ce2 = *(const float2*)(ws + OFF_CE + jb);
        #pragma unroll
        for (int i = 0; i < 8; ++i) {
            float rc0 = r[i][0] + ce2.x, rc1 = r[i][1] + ce2.y;
            float M = fmaxf(rc0, rc1);
            float S = __builtin_amdgcn_exp2f(rc0 - M) + __builtin_amdgcn_exp2f(rc1 - M);
            #pragma unroll
            for (int off = 32; off > 0; off >>= 1) {
                float Mo = __shfl_xor(M, off, 64);
                float So = __shfl_xor(S, off, 64);
                float mn = fmaxf(M, Mo);
                S = S * __builtin_amdgcn_exp2f(M - mn) + So * __builtin_amdgcn_exp2f(Mo - mn);
                M = mn;
            }
            if (lane == 0) { RMs[i][w] = M; RSs[i][w] = S; }
        }
        __syncthreads();
        if (t < 8) {
            float M = RMs[t][0], S = RSs[t][0];
            #pragma unroll
            for (int w2 = 1; w2 < 4; ++w2) {
                float Mo = RMs[t][w2], So = RSs[t][w2];
                float mn = fmaxf(M, Mo);
                S = S * __builtin_amdgcn_exp2f(M - mn) + So * __builtin_amdgcn_exp2f(Mo - mn);
                M = mn;
            }
            ws[OFF_RMP + qh * BATCH + i0 + t] = M;
            ws[OFF_RSP + qh * BATCH + i0 + t] = S;
        }
    }

    // ---- done-counter; last block finalizes ----
    __threadfence();
    if (t == 0) {
        unsigned prev = atomicAdd((unsigned*)(ws + OFF_PART + 2), 1u);
        is_last = (prev == 2047u) ? 1 : 0;
    }
    __syncthreads();
    if (is_last) {
        __threadfence();
        float acc = 0.0f, kl = 0.0f;
        // -sum_{l,i} log2(PPS): 131072 elems, 512 per thread
        #pragma unroll 4
        for (int k = 0; k < 512; ++k)
            acc -= __builtin_amdgcn_logf(ws[OFF_PPS + k * 256 + t]);
        // +sum_i lqz_i (merge 4 quarters), +KL
        #pragma unroll
        for (int k = 0; k < 8; ++k) {
            int i = k * 256 + t;
            float M = ws[OFF_RMP + i];
            float S = ws[OFF_RSP + i];
            #pragma unroll
            for (int q = 1; q < 4; ++q) {
                float Mo = ws[OFF_RMP + q * BATCH + i];
                float So = ws[OFF_RSP + q * BATCH + i];
                float mn = fmaxf(M, Mo);
                S = S * __builtin_amdgcn_exp2f(M - mn) + So * __builtin_amdgcn_exp2f(Mo - mn);
                M = mn;
            }
            acc += M + __builtin_amdgcn_logf(S);
            kl  += ws[OFF_KLP + i];
        }
        s_tc[t] = acc; s_kl[t] = kl;
        __syncthreads();
        for (int s = 128; s > 0; s >>= 1) {
            if (t < s) { s_tc[t] += s_tc[t + s]; s_kl[t] += s_kl[t + s]; }
            __syncthreads();
        }
        if (t == 0)
            out[0] = BETA_M1 * (LN2 * s_tc[0] / (float)BATCH)
                   + 0.5f * (s_kl[0] / (float)BATCH);
    }
}

extern "C" void kernel_launch(void* const* d_in, const int* in_sizes, int n_in,
                              void* d_out, int out_size, void* d_ws, size_t ws_size,
                              hipStream_t stream) {
    const float* z        = (const float*)d_in[0];
    const float* z_mean   = (const float*)d_in[1];
    const float* z_logvar = (const float*)d_in[2];
    float* out = (float*)d_out;
    float* ws  = (float*)d_ws;

    pre_kernel<<<128, 256, 0, stream>>>(z, z_mean, z_logvar, ws);
    main_kernel<<<2048, 256, 0, stream>>>(ws, out);
}